// Round 3
// baseline (225.034 us; speedup 1.0000x reference)
//
#include <hip/hip_runtime.h>

// Problem constants
#define NN 8192
#define EE 65536
#define ZSTRIDE 20  // 16 nodes + 4 pad, keeps 16B alignment for float4 LDS reads

// ---------------------------------------------------------------------------
// Bilinear factorization: per-edge weight matrices are never materialized.
//   Layer1: Z1[d,f,i] = sum_{e->d} ea[e][f]*x[src][i]  (f<8), plus sum_x and
//   self-x rows; then one GEMM [16 nodes x 640] @ [640 x 48] per block with
//   W = [nn1_w | nn1_b | root1] (all have flat layout base[k*48+o]).
//   Layer2: same with h1, K=480, 32 cols. GCN: CSR gather, no atomics.
// ---------------------------------------------------------------------------

__global__ __launch_bounds__(256) void k_zero(int* __restrict__ p) {
    int i = blockIdx.x * 256 + threadIdx.x;
    ((int4*)p)[i] = make_int4(0, 0, 0, 0);  // grid covers exactly 8192 ints
}

__global__ __launch_bounds__(256) void k_count(const int* __restrict__ ei,
                                               int* __restrict__ cnt) {
    int e = blockIdx.x * 256 + threadIdx.x;
    if (e < EE) atomicAdd(&cnt[ei[EE + e]], 1);
}

// Single block: exclusive scan cnt[8192] -> rowstart[8193] and cursor[8192].
__global__ __launch_bounds__(256) void k_scan(const int* __restrict__ cnt,
                                              int* __restrict__ rowstart,
                                              int* __restrict__ cursor) {
    __shared__ int part[256];
    const int t = threadIdx.x;
    const int base = t * 32;
    int local[32];
    int sum = 0;
#pragma unroll
    for (int k = 0; k < 32; k++) { local[k] = cnt[base + k]; sum += local[k]; }
    part[t] = sum;
    __syncthreads();
    if (t == 0) {
        int run = 0;
        for (int i = 0; i < 256; i++) { int c = part[i]; part[i] = run; run += c; }
    }
    __syncthreads();
    int run = part[t];
#pragma unroll
    for (int k = 0; k < 32; k++) {
        rowstart[base + k] = run;
        cursor[base + k] = run;
        run += local[k];
    }
    if (t == 255) rowstart[NN] = run;  // == EE
}

// dst-sorted edge arrays: ssrc (source node) and sea (edge features, coalesced).
__global__ __launch_bounds__(256) void k_scatter(const int* __restrict__ ei,
                                                 const float* __restrict__ ea,
                                                 int* __restrict__ cursor,
                                                 int* __restrict__ ssrc,
                                                 float* __restrict__ sea) {
    int e = blockIdx.x * 256 + threadIdx.x;
    if (e >= EE) return;
    int s = ei[e], d = ei[EE + e];
    int pos = atomicAdd(&cursor[d], 1);
    ssrc[pos] = s;
    const float4* a = (const float4*)(ea + (size_t)e * 8);
    float4* bp = (float4*)(sea + (size_t)pos * 8);
    bp[0] = a[0];
    bp[1] = a[1];
}

// ---------------------------------------------------------------------------
// k_L1: per block of 16 nodes:
//  phase A: build Zt[640][16] in LDS (transposed): k<512: Z1[f*64+i];
//           512..575: sum_x[i]; 576..639: x_self[i]
//  phase B: register-tiled GEMM: thread=(o16,q,ks): 3 cols x 4 nodes x K/4
//  phase C: reduce 4 K-partials, +bias1, relu -> h1
// ---------------------------------------------------------------------------
__global__ __launch_bounds__(256) void k_L1(const int* __restrict__ rowstart,
                                            const int* __restrict__ ssrc,
                                            const float* __restrict__ sea,
                                            const float* __restrict__ x,
                                            const float* __restrict__ nn1_w,
                                            const float* __restrict__ nn1_b,
                                            const float* __restrict__ root1,
                                            const float* __restrict__ bias1,
                                            float* __restrict__ h1) {
    __shared__ __align__(16) float Zt[640 * ZSTRIDE];
    __shared__ float pacc[4 * 48 * 16];
    const int n0 = blockIdx.x * 16;
    {
        const int g = threadIdx.x >> 6;  // wave id: node sub-group
        const int i = threadIdx.x & 63;
        for (int nb = 0; nb < 16; nb += 4) {
            const int nn = nb + g;
            const int n = n0 + nn;
            const int rs = rowstart[n], re = rowstart[n + 1];
            float a0 = 0, a1 = 0, a2 = 0, a3 = 0, a4 = 0, a5 = 0, a6 = 0, a7 = 0, as = 0;
            for (int j = rs; j < re; ++j) {
                int s = ssrc[j];
                float xv = x[(size_t)s * 64 + i];
                const float4* q4 = (const float4*)(sea + (size_t)j * 8);
                float4 e0 = q4[0], e1 = q4[1];
                a0 += e0.x * xv; a1 += e0.y * xv; a2 += e0.z * xv; a3 += e0.w * xv;
                a4 += e1.x * xv; a5 += e1.y * xv; a6 += e1.z * xv; a7 += e1.w * xv;
                as += xv;
            }
            Zt[(0 * 64 + i) * ZSTRIDE + nn] = a0;
            Zt[(1 * 64 + i) * ZSTRIDE + nn] = a1;
            Zt[(2 * 64 + i) * ZSTRIDE + nn] = a2;
            Zt[(3 * 64 + i) * ZSTRIDE + nn] = a3;
            Zt[(4 * 64 + i) * ZSTRIDE + nn] = a4;
            Zt[(5 * 64 + i) * ZSTRIDE + nn] = a5;
            Zt[(6 * 64 + i) * ZSTRIDE + nn] = a6;
            Zt[(7 * 64 + i) * ZSTRIDE + nn] = a7;
            Zt[(512 + i) * ZSTRIDE + nn] = as;
            Zt[(576 + i) * ZSTRIDE + nn] = x[(size_t)n * 64 + i];
        }
    }
    __syncthreads();
    {
        const int o = threadIdx.x & 15;
        const int q = (threadIdx.x >> 4) & 3;
        const int ks = threadIdx.x >> 6;
        const int k0 = ks * 160, k1 = k0 + 160;
        float4 c0 = {0, 0, 0, 0}, c1 = {0, 0, 0, 0}, c2 = {0, 0, 0, 0};
        const int zb = q * 4;
        // region A: nn1_w, k in [k0, min(k1,512))
        int ka1 = k1 < 512 ? k1 : 512;
        for (int k = k0; k < ka1; ++k) {
            const float* wp = nn1_w + k * 48 + o;
            float w0 = wp[0], w1 = wp[16], w2 = wp[32];
            float4 z = *(const float4*)&Zt[k * ZSTRIDE + zb];
            c0.x += z.x * w0; c0.y += z.y * w0; c0.z += z.z * w0; c0.w += z.w * w0;
            c1.x += z.x * w1; c1.y += z.y * w1; c1.z += z.z * w1; c1.w += z.w * w1;
            c2.x += z.x * w2; c2.y += z.y * w2; c2.z += z.z * w2; c2.w += z.w * w2;
        }
        // region B: nn1_b, k in [max(k0,512), min(k1,576))
        int kb0 = k0 > 512 ? k0 : 512, kb1 = k1 < 576 ? k1 : 576;
        for (int k = kb0; k < kb1; ++k) {
            const float* wp = nn1_b + (k - 512) * 48 + o;
            float w0 = wp[0], w1 = wp[16], w2 = wp[32];
            float4 z = *(const float4*)&Zt[k * ZSTRIDE + zb];
            c0.x += z.x * w0; c0.y += z.y * w0; c0.z += z.z * w0; c0.w += z.w * w0;
            c1.x += z.x * w1; c1.y += z.y * w1; c1.z += z.z * w1; c1.w += z.w * w1;
            c2.x += z.x * w2; c2.y += z.y * w2; c2.z += z.z * w2; c2.w += z.w * w2;
        }
        // region C: root1, k in [max(k0,576), k1)
        int kc0 = k0 > 576 ? k0 : 576;
        for (int k = kc0; k < k1; ++k) {
            const float* wp = root1 + (k - 576) * 48 + o;
            float w0 = wp[0], w1 = wp[16], w2 = wp[32];
            float4 z = *(const float4*)&Zt[k * ZSTRIDE + zb];
            c0.x += z.x * w0; c0.y += z.y * w0; c0.z += z.z * w0; c0.w += z.w * w0;
            c1.x += z.x * w1; c1.y += z.y * w1; c1.z += z.z * w1; c1.w += z.w * w1;
            c2.x += z.x * w2; c2.y += z.y * w2; c2.z += z.z * w2; c2.w += z.w * w2;
        }
        float* pp = pacc + (ks * 48 + o) * 16 + zb;
        pp[0] = c0.x; pp[1] = c0.y; pp[2] = c0.z; pp[3] = c0.w;
        pp = pacc + (ks * 48 + o + 16) * 16 + zb;
        pp[0] = c1.x; pp[1] = c1.y; pp[2] = c1.z; pp[3] = c1.w;
        pp = pacc + (ks * 48 + o + 32) * 16 + zb;
        pp[0] = c2.x; pp[1] = c2.y; pp[2] = c2.z; pp[3] = c2.w;
    }
    __syncthreads();
    for (int r = threadIdx.x; r < 768; r += 256) {
        int o = r >> 4, n = r & 15;
        float v = pacc[(0 * 48 + o) * 16 + n] + pacc[(1 * 48 + o) * 16 + n] +
                  pacc[(2 * 48 + o) * 16 + n] + pacc[(3 * 48 + o) * 16 + n] + bias1[o];
        h1[(size_t)(n0 + n) * 48 + o] = v > 0.f ? v : 0.f;
    }
}

// ---------------------------------------------------------------------------
// k_L2: same pattern, K=480 (384 Z2 + 48 sum_h1 + 48 h1_self), 32 cols.
// Epilogue fuses old k_post: h2 -> hmu/hls matvecs, dinv, out self-loop init.
// ---------------------------------------------------------------------------
__global__ __launch_bounds__(256) void k_L2(const int* __restrict__ rowstart,
                                            const int* __restrict__ ssrc,
                                            const float* __restrict__ sea,
                                            const float* __restrict__ h1,
                                            const float* __restrict__ nn2_w,
                                            const float* __restrict__ nn2_b,
                                            const float* __restrict__ root2,
                                            const float* __restrict__ bias2,
                                            const float* __restrict__ mu_w,
                                            const float* __restrict__ mu_b,
                                            const float* __restrict__ ls_w,
                                            const float* __restrict__ ls_b,
                                            const int* __restrict__ cnt,
                                            float* __restrict__ hmu,
                                            float* __restrict__ hls,
                                            float* __restrict__ dinv,
                                            float* __restrict__ out) {
    __shared__ __align__(16) float Zt[480 * ZSTRIDE];
    __shared__ float pacc[4 * 32 * 16];
    __shared__ float h2s[16 * 33];
    const int n0 = blockIdx.x * 16;
    {
        const int g = threadIdx.x >> 6;
        const int i = threadIdx.x & 63;
        for (int nb = 0; nb < 16; nb += 4) {
            const int nn = nb + g;
            const int n = n0 + nn;
            if (i < 48) {
                const int rs = rowstart[n], re = rowstart[n + 1];
                float a0 = 0, a1 = 0, a2 = 0, a3 = 0, a4 = 0, a5 = 0, a6 = 0, a7 = 0, as = 0;
                for (int j = rs; j < re; ++j) {
                    int s = ssrc[j];
                    float hv = h1[(size_t)s * 48 + i];
                    const float4* q4 = (const float4*)(sea + (size_t)j * 8);
                    float4 e0 = q4[0], e1 = q4[1];
                    a0 += e0.x * hv; a1 += e0.y * hv; a2 += e0.z * hv; a3 += e0.w * hv;
                    a4 += e1.x * hv; a5 += e1.y * hv; a6 += e1.z * hv; a7 += e1.w * hv;
                    as += hv;
                }
                Zt[(0 * 48 + i) * ZSTRIDE + nn] = a0;
                Zt[(1 * 48 + i) * ZSTRIDE + nn] = a1;
                Zt[(2 * 48 + i) * ZSTRIDE + nn] = a2;
                Zt[(3 * 48 + i) * ZSTRIDE + nn] = a3;
                Zt[(4 * 48 + i) * ZSTRIDE + nn] = a4;
                Zt[(5 * 48 + i) * ZSTRIDE + nn] = a5;
                Zt[(6 * 48 + i) * ZSTRIDE + nn] = a6;
                Zt[(7 * 48 + i) * ZSTRIDE + nn] = a7;
                Zt[(384 + i) * ZSTRIDE + nn] = as;
                Zt[(432 + i) * ZSTRIDE + nn] = h1[(size_t)n * 48 + i];
            }
        }
    }
    __syncthreads();
    {
        const int o = threadIdx.x & 15;
        const int q = (threadIdx.x >> 4) & 3;
        const int ks = threadIdx.x >> 6;
        const int k0 = ks * 120, k1 = k0 + 120;
        float4 c0 = {0, 0, 0, 0}, c1 = {0, 0, 0, 0};
        const int zb = q * 4;
        int ka1 = k1 < 384 ? k1 : 384;
        for (int k = k0; k < ka1; ++k) {
            const float* wp = nn2_w + k * 32 + o;
            float w0 = wp[0], w1 = wp[16];
            float4 z = *(const float4*)&Zt[k * ZSTRIDE + zb];
            c0.x += z.x * w0; c0.y += z.y * w0; c0.z += z.z * w0; c0.w += z.w * w0;
            c1.x += z.x * w1; c1.y += z.y * w1; c1.z += z.z * w1; c1.w += z.w * w1;
        }
        int kb0 = k0 > 384 ? k0 : 384, kb1 = k1 < 432 ? k1 : 432;
        for (int k = kb0; k < kb1; ++k) {
            const float* wp = nn2_b + (k - 384) * 32 + o;
            float w0 = wp[0], w1 = wp[16];
            float4 z = *(const float4*)&Zt[k * ZSTRIDE + zb];
            c0.x += z.x * w0; c0.y += z.y * w0; c0.z += z.z * w0; c0.w += z.w * w0;
            c1.x += z.x * w1; c1.y += z.y * w1; c1.z += z.z * w1; c1.w += z.w * w1;
        }
        int kc0 = k0 > 432 ? k0 : 432;
        for (int k = kc0; k < k1; ++k) {
            const float* wp = root2 + (k - 432) * 32 + o;
            float w0 = wp[0], w1 = wp[16];
            float4 z = *(const float4*)&Zt[k * ZSTRIDE + zb];
            c0.x += z.x * w0; c0.y += z.y * w0; c0.z += z.z * w0; c0.w += z.w * w0;
            c1.x += z.x * w1; c1.y += z.y * w1; c1.z += z.z * w1; c1.w += z.w * w1;
        }
        float* pp = pacc + (ks * 32 + o) * 16 + zb;
        pp[0] = c0.x; pp[1] = c0.y; pp[2] = c0.z; pp[3] = c0.w;
        pp = pacc + (ks * 32 + o + 16) * 16 + zb;
        pp[0] = c1.x; pp[1] = c1.y; pp[2] = c1.z; pp[3] = c1.w;
    }
    __syncthreads();
    for (int r = threadIdx.x; r < 512; r += 256) {
        int o = r >> 4, n = r & 15;
        float v = pacc[(0 * 32 + o) * 16 + n] + pacc[(1 * 32 + o) * 16 + n] +
                  pacc[(2 * 32 + o) * 16 + n] + pacc[(3 * 32 + o) * 16 + n] + bias2[o];
        h2s[n * 33 + o] = v > 0.f ? v : 0.f;
    }
    __syncthreads();
    {
        const int n = threadIdx.x >> 4;
        const int o = threadIdx.x & 15;
        const int gn = n0 + n;
        float am = 0.f, al = 0.f;
#pragma unroll
        for (int i = 0; i < 32; i++) {
            float hv = h2s[n * 33 + i];
            am += hv * mu_w[i * 16 + o];
            al += hv * ls_w[i * 16 + o];
        }
        float d = (float)cnt[gn] + 1.0f;
        float di = rsqrtf(d);
        if (o == 0) dinv[gn] = di;
        hmu[(size_t)gn * 16 + o] = am;
        hls[(size_t)gn * 16 + o] = al;
        out[(size_t)gn * 16 + o] = am / d + mu_b[o];
        out[(size_t)NN * 16 + (size_t)gn * 16 + o] = al / d + ls_b[o];
    }
}

// Final GCN neighbor sums: CSR gather, plain RMW on out (one owner per elem).
__global__ __launch_bounds__(256) void k_gcn(const int* __restrict__ rowstart,
                                             const int* __restrict__ ssrc,
                                             const float* __restrict__ hmu,
                                             const float* __restrict__ hls,
                                             const float* __restrict__ dinv,
                                             float* __restrict__ out) {
    int idx = blockIdx.x * 256 + threadIdx.x;  // grid covers 8192*16 exactly
    int d = idx >> 4, o = idx & 15;
    const int rs = rowstart[d], re = rowstart[d + 1];
    float am = 0.f, al = 0.f;
    for (int j = rs; j < re; ++j) {
        int s = ssrc[j];
        float ds_ = dinv[s];
        am += hmu[(size_t)s * 16 + o] * ds_;
        al += hls[(size_t)s * 16 + o] * ds_;
    }
    float dd = dinv[d];
    out[(size_t)d * 16 + o] += am * dd;
    out[(size_t)NN * 16 + (size_t)d * 16 + o] += al * dd;
}

extern "C" void kernel_launch(void* const* d_in, const int* in_sizes, int n_in,
                              void* d_out, int out_size, void* d_ws, size_t ws_size,
                              hipStream_t stream) {
    const float* x     = (const float*)d_in[0];
    const int*   ei    = (const int*)d_in[1];
    const float* ea    = (const float*)d_in[2];
    const float* nn1_w = (const float*)d_in[3];
    const float* nn1_b = (const float*)d_in[4];
    const float* root1 = (const float*)d_in[5];
    const float* bias1 = (const float*)d_in[6];
    const float* nn2_w = (const float*)d_in[7];
    const float* nn2_b = (const float*)d_in[8];
    const float* root2 = (const float*)d_in[9];
    const float* bias2 = (const float*)d_in[10];
    const float* mu_w  = (const float*)d_in[11];
    const float* mu_b  = (const float*)d_in[12];
    const float* ls_w  = (const float*)d_in[13];
    const float* ls_b  = (const float*)d_in[14];
    float* out = (float*)d_out;

    // Workspace layout (floats/ints). Total ~5.4 MB — everything L2-resident.
    float* W    = (float*)d_ws;
    float* sea  = W;                        // 524,288 (16B aligned at base)
    float* h1   = sea + 524288;             // 393,216
    float* hmu  = h1 + 393216;              // 131,072
    float* hls  = hmu + 131072;             // 131,072
    float* dinv = hls + 131072;             // 8,192
    int* cnt      = (int*)(dinv + 8192);    // 8,192
    int* rowstart = cnt + 8192;             // 8,193
    int* cursor   = rowstart + 8193;        // 8,192 (pad to even elsewhere ok)
    int* ssrc     = cursor + 8192;          // 65,536

    k_zero<<<dim3(8), dim3(256), 0, stream>>>(cnt);                 // 2048 int4
    k_count<<<dim3(EE / 256), dim3(256), 0, stream>>>(ei, cnt);
    k_scan<<<dim3(1), dim3(256), 0, stream>>>(cnt, rowstart, cursor);
    k_scatter<<<dim3(EE / 256), dim3(256), 0, stream>>>(ei, ea, cursor, ssrc, sea);
    k_L1<<<dim3(NN / 16), dim3(256), 0, stream>>>(rowstart, ssrc, sea, x,
                                                  nn1_w, nn1_b, root1, bias1, h1);
    k_L2<<<dim3(NN / 16), dim3(256), 0, stream>>>(rowstart, ssrc, sea, h1,
                                                  nn2_w, nn2_b, root2, bias2,
                                                  mu_w, mu_b, ls_w, ls_b, cnt,
                                                  hmu, hls, dinv, out);
    k_gcn<<<dim3((NN * 16) / 256), dim3(256), 0, stream>>>(rowstart, ssrc,
                                                           hmu, hls, dinv, out);
}